// Round 1
// baseline (2785.367 us; speedup 1.0000x reference)
//
#include <hip/hip_runtime.h>
#include <math.h>

#define N_NODES 50000
#define N_EDGES 800000
#define HID 512

#define BM 64
#define BN 64
#define BK 32

// ---------------- CSR build ----------------

__global__ void zero_kernel(int* __restrict__ p, int n) {
    int i = blockIdx.x * blockDim.x + threadIdx.x;
    if (i < n) p[i] = 0;
}

// Detect whether edge_index is int64 (JAX x64 enabled) or int32 (default).
// For int64 little-endian non-negative values < 50000, every odd int32 is 0.
__global__ void detect_kernel(const int* __restrict__ e, int* __restrict__ flag) {
    if (blockIdx.x == 0 && threadIdx.x == 0) {
        int is64 = 1;
        for (int i = 0; i < 16; ++i)
            if (e[2 * i + 1] != 0) is64 = 0;
        *flag = is64;
    }
}

__global__ void hist_kernel(const void* __restrict__ eidx, const int* __restrict__ flag,
                            int* __restrict__ counts) {
    int e = blockIdx.x * blockDim.x + threadIdx.x;
    if (e >= N_EDGES) return;
    int is64 = *flag;
    int d;
    if (is64) d = (int)((const long long*)eidx)[N_EDGES + e];
    else      d = ((const int*)eidx)[N_EDGES + e];
    atomicAdd(&counts[d], 1);
}

// Single-block scan: 1024 threads, each owns a contiguous chunk of nodes.
__global__ __launch_bounds__(1024) void scan_kernel(const int* __restrict__ counts,
                                                    int* __restrict__ offsets) {
    __shared__ int sums[1024];
    int t = threadIdx.x;
    const int CH = (N_NODES + 1023) / 1024;  // 49
    int lo = t * CH;
    int hi = min(lo + CH, N_NODES);
    int s = 0;
    for (int i = lo; i < hi; ++i) s += counts[i];
    sums[t] = s;
    __syncthreads();
    for (int off = 1; off < 1024; off <<= 1) {
        int v = 0;
        if (t >= off) v = sums[t - off];
        __syncthreads();
        sums[t] += v;
        __syncthreads();
    }
    int excl = (t == 0) ? 0 : sums[t - 1];
    for (int i = lo; i < hi; ++i) { offsets[i] = excl; excl += counts[i]; }
    if (t == 1023) offsets[N_NODES] = excl;
}

__global__ void fill_kernel(const void* __restrict__ eidx, const int* __restrict__ flag,
                            const int* __restrict__ offsets, int* __restrict__ cursor,
                            int* __restrict__ edge_src) {
    int e = blockIdx.x * blockDim.x + threadIdx.x;
    if (e >= N_EDGES) return;
    int is64 = *flag;
    int s, d;
    if (is64) {
        const long long* p = (const long long*)eidx;
        s = (int)p[e];
        d = (int)p[N_EDGES + e];
    } else {
        const int* p = (const int*)eidx;
        s = p[e];
        d = p[N_EDGES + e];
    }
    int pos = atomicAdd(&cursor[d], 1);
    edge_src[offsets[d] + pos] = s;
}

// ---------------- aggregate: agg[node] = sum over in-edges of feat[src] ----------------

__global__ __launch_bounds__(256) void aggregate_kernel(const float* __restrict__ feat,
                                                        const int* __restrict__ offsets,
                                                        const int* __restrict__ edge_src,
                                                        float* __restrict__ agg, int W) {
    int node = blockIdx.x;
    int t = threadIdx.x;
    int beg = offsets[node], end = offsets[node + 1];
    if (W == 256) {
        float a = 0.f;
        for (int i = beg; i < end; ++i) {
            int s = edge_src[i];
            a += feat[(size_t)s * 256 + t];
        }
        agg[(size_t)node * 256 + t] = a;
    } else {
        float a0 = 0.f, a1 = 0.f;
        for (int i = beg; i < end; ++i) {
            int s = edge_src[i];
            const float* r = feat + (size_t)s * 512;
            a0 += r[t];
            a1 += r[t + 256];
        }
        agg[(size_t)node * 512 + t] = a0;
        agg[(size_t)node * 512 + t + 256] = a1;
    }
}

// ---------------- fused dual GEMM: out = A1@W1 + A2@W2 + bias ----------------
// A1,A2: [N_NODES, K1]  W1,W2: [K1, HID]  out: [N_NODES, HID]

__global__ __launch_bounds__(256) void gemm_dual_kernel(
    const float* __restrict__ A1, const float* __restrict__ A2,
    const float* __restrict__ W1, const float* __restrict__ W2,
    const float* __restrict__ bias, float* __restrict__ out, int K1) {
    __shared__ float As[BK][BM + 4];  // transposed: As[k][m]
    __shared__ float Bs[BK][BN + 4];
    const int bm = blockIdx.y * BM;
    const int bn = blockIdx.x * BN;
    const int tid = threadIdx.x;
    const int tx = tid & 15;
    const int ty = tid >> 4;
    float acc[4][4] = {{0.f}};

    const int nkt = (2 * K1) / BK;
    for (int kt = 0; kt < nkt; ++kt) {
        int k0 = kt * BK;
        const float* A;
        const float* W;
        int kb;
        if (k0 < K1) { A = A1; W = W1; kb = k0; }
        else         { A = A2; W = W2; kb = k0 - K1; }

        // load A tile 64x32 (512 float4, 2 per thread), store transposed
#pragma unroll
        for (int l = 0; l < 2; ++l) {
            int id = tid + l * 256;
            int row = id >> 3;
            int c4 = id & 7;
            int gr = bm + row;
            float4 v = make_float4(0.f, 0.f, 0.f, 0.f);
            if (gr < N_NODES) v = *(const float4*)(A + (size_t)gr * K1 + kb + c4 * 4);
            As[c4 * 4 + 0][row] = v.x;
            As[c4 * 4 + 1][row] = v.y;
            As[c4 * 4 + 2][row] = v.z;
            As[c4 * 4 + 3][row] = v.w;
        }
        // load W tile 32x64 (512 float4, 2 per thread)
#pragma unroll
        for (int l = 0; l < 2; ++l) {
            int id = tid + l * 256;
            int kr = id >> 4;
            int c4 = id & 15;
            float4 v = *(const float4*)(W + (size_t)(kb + kr) * HID + bn + c4 * 4);
            *(float4*)&Bs[kr][c4 * 4] = v;
        }
        __syncthreads();

#pragma unroll
        for (int k = 0; k < BK; ++k) {
            float4 a = *(const float4*)&As[k][ty * 4];
            float4 b = *(const float4*)&Bs[k][tx * 4];
            acc[0][0] += a.x * b.x; acc[0][1] += a.x * b.y; acc[0][2] += a.x * b.z; acc[0][3] += a.x * b.w;
            acc[1][0] += a.y * b.x; acc[1][1] += a.y * b.y; acc[1][2] += a.y * b.z; acc[1][3] += a.y * b.w;
            acc[2][0] += a.z * b.x; acc[2][1] += a.z * b.y; acc[2][2] += a.z * b.z; acc[2][3] += a.z * b.w;
            acc[3][0] += a.w * b.x; acc[3][1] += a.w * b.y; acc[3][2] += a.w * b.z; acc[3][3] += a.w * b.w;
        }
        __syncthreads();
    }

    float4 bv = *(const float4*)(bias + bn + tx * 4);
#pragma unroll
    for (int i = 0; i < 4; ++i) {
        int gr = bm + ty * 4 + i;
        if (gr < N_NODES) {
            float4 o;
            o.x = acc[i][0] + bv.x;
            o.y = acc[i][1] + bv.y;
            o.z = acc[i][2] + bv.z;
            o.w = acc[i][3] + bv.w;
            *(float4*)(out + (size_t)gr * HID + bn + tx * 4) = o;
        }
    }
}

// ---------------- row L2-normalize + ELU (in place) ----------------

__global__ __launch_bounds__(128) void norm_elu_kernel(float* __restrict__ data) {
    int row = blockIdx.x;
    int t = threadIdx.x;
    float* p = data + (size_t)row * HID + t * 4;
    float4 v = *(float4*)p;
    float ss = v.x * v.x + v.y * v.y + v.z * v.z + v.w * v.w;
#pragma unroll
    for (int o = 32; o > 0; o >>= 1) ss += __shfl_down(ss, o);
    __shared__ float w0, w1;
    if (t == 0) w0 = ss;
    if (t == 64) w1 = ss;
    __syncthreads();
    float norm = sqrtf(w0 + w1);
    norm = fmaxf(norm, 1e-12f);
    float inv = 1.f / norm;
    v.x *= inv; v.y *= inv; v.z *= inv; v.w *= inv;
    v.x = v.x > 0.f ? v.x : expm1f(v.x);
    v.y = v.y > 0.f ? v.y : expm1f(v.y);
    v.z = v.z > 0.f ? v.z : expm1f(v.z);
    v.w = v.w > 0.f ? v.w : expm1f(v.w);
    *(float4*)p = v;
}

// ---------------- launch ----------------

extern "C" void kernel_launch(void* const* d_in, const int* in_sizes, int n_in,
                              void* d_out, int out_size, void* d_ws, size_t ws_size,
                              hipStream_t stream) {
    const float* x    = (const float*)d_in[0];
    const void*  eidx = d_in[1];
    const float* Wl0 = (const float*)d_in[2];
    const float* bl0 = (const float*)d_in[3];
    const float* Wr0 = (const float*)d_in[4];
    const float* Wl1 = (const float*)d_in[5];
    const float* bl1 = (const float*)d_in[6];
    const float* Wr1 = (const float*)d_in[7];
    const float* Wl2 = (const float*)d_in[8];
    const float* bl2 = (const float*)d_in[9];
    const float* Wr2 = (const float*)d_in[10];
    float* out = (float*)d_out;

    char* ws = (char*)d_ws;
    float* agg = (float*)ws;                               // N*512 f32
    float* fA  = agg + (size_t)N_NODES * 512;              // N*512 f32
    int* counts   = (int*)(fA + (size_t)N_NODES * 512);    // N int
    int* cursor   = counts + N_NODES;                      // N int
    int* offsets  = cursor + N_NODES;                      // N+1 int
    int* edge_src = offsets + N_NODES + 1;                 // E int
    int* flag     = edge_src + N_EDGES;                    // 1 int

    // ---- CSR build (once per call, reused for all 3 layers) ----
    zero_kernel<<<(2 * N_NODES + 255) / 256, 256, 0, stream>>>(counts, 2 * N_NODES);
    detect_kernel<<<1, 64, 0, stream>>>((const int*)eidx, flag);
    hist_kernel<<<(N_EDGES + 255) / 256, 256, 0, stream>>>(eidx, flag, counts);
    scan_kernel<<<1, 1024, 0, stream>>>(counts, offsets);
    fill_kernel<<<(N_EDGES + 255) / 256, 256, 0, stream>>>(eidx, flag, offsets, cursor, edge_src);

    dim3 ggrid(HID / BN, (N_NODES + BM - 1) / BM);

    // layer 1: x (256) -> out
    aggregate_kernel<<<N_NODES, 256, 0, stream>>>(x, offsets, edge_src, agg, 256);
    gemm_dual_kernel<<<ggrid, 256, 0, stream>>>(agg, x, Wl0, Wr0, bl0, out, 256);
    norm_elu_kernel<<<N_NODES, 128, 0, stream>>>(out);

    // layer 2: out (512) -> fA
    aggregate_kernel<<<N_NODES, 256, 0, stream>>>(out, offsets, edge_src, agg, 512);
    gemm_dual_kernel<<<ggrid, 256, 0, stream>>>(agg, out, Wl1, Wr1, bl1, fA, 512);
    norm_elu_kernel<<<N_NODES, 128, 0, stream>>>(fA);

    // layer 3: fA (512) -> out
    aggregate_kernel<<<N_NODES, 256, 0, stream>>>(fA, offsets, edge_src, agg, 512);
    gemm_dual_kernel<<<ggrid, 256, 0, stream>>>(agg, fA, Wl2, Wr2, bl2, out, 512);
    norm_elu_kernel<<<N_NODES, 128, 0, stream>>>(out);

    (void)in_sizes; (void)n_in; (void)out_size; (void)ws_size;
}

// Round 4
// 1030.937 us; speedup vs baseline: 2.7018x; 2.7018x over previous
//
#include <hip/hip_runtime.h>
#include <math.h>

#define N_NODES 50000
#define M_PAD   50048   // 391 * 128
#define N_EDGES 800000
#define HID 512

typedef short bf16x8 __attribute__((ext_vector_type(8)));
typedef float f32x4  __attribute__((ext_vector_type(4)));

__device__ inline float b2f(unsigned short u) {
    union { unsigned int i; float f; } v; v.i = ((unsigned int)u) << 16; return v.f;
}
__device__ inline unsigned short f2b(float f) {
    union { float f; unsigned int i; } v; v.f = f;
    unsigned int r = v.i + 0x7FFFu + ((v.i >> 16) & 1u);
    return (unsigned short)(r >> 16);
}

// ---------------- CSR build ----------------

__global__ void zero_kernel(int* __restrict__ p, int n) {
    int i = blockIdx.x * blockDim.x + threadIdx.x;
    if (i < n) p[i] = 0;
}

__global__ void detect_kernel(const int* __restrict__ e, int* __restrict__ flag) {
    if (blockIdx.x == 0 && threadIdx.x == 0) {
        int is64 = 1;
        for (int i = 0; i < 16; ++i)
            if (e[2 * i + 1] != 0) is64 = 0;
        *flag = is64;
    }
}

__global__ void hist_kernel(const void* __restrict__ eidx, const int* __restrict__ flag,
                            int* __restrict__ counts) {
    int e = blockIdx.x * blockDim.x + threadIdx.x;
    if (e >= N_EDGES) return;
    int is64 = *flag;
    int d;
    if (is64) d = (int)((const long long*)eidx)[N_EDGES + e];
    else      d = ((const int*)eidx)[N_EDGES + e];
    atomicAdd(&counts[d], 1);
}

__global__ __launch_bounds__(1024) void scan_kernel(const int* __restrict__ counts,
                                                    int* __restrict__ offsets) {
    __shared__ int sums[1024];
    int t = threadIdx.x;
    const int CH = (N_NODES + 1023) / 1024;  // 49
    int lo = t * CH;
    int hi = min(lo + CH, N_NODES);
    int s = 0;
    for (int i = lo; i < hi; ++i) s += counts[i];
    sums[t] = s;
    __syncthreads();
    for (int off = 1; off < 1024; off <<= 1) {
        int v = 0;
        if (t >= off) v = sums[t - off];
        __syncthreads();
        sums[t] += v;
        __syncthreads();
    }
    int excl = (t == 0) ? 0 : sums[t - 1];
    for (int i = lo; i < hi; ++i) { offsets[i] = excl; excl += counts[i]; }
    if (t == 1023) offsets[N_NODES] = excl;
}

__global__ void fill_kernel(const void* __restrict__ eidx, const int* __restrict__ flag,
                            const int* __restrict__ offsets, int* __restrict__ cursor,
                            int* __restrict__ edge_src) {
    int e = blockIdx.x * blockDim.x + threadIdx.x;
    if (e >= N_EDGES) return;
    int is64 = *flag;
    int s, d;
    if (is64) {
        const long long* p = (const long long*)eidx;
        s = (int)p[e];
        d = (int)p[N_EDGES + e];
    } else {
        const int* p = (const int*)eidx;
        s = p[e];
        d = p[N_EDGES + e];
    }
    int pos = atomicAdd(&cursor[d], 1);
    edge_src[offsets[d] + pos] = s;
}

// ---------------- conversions ----------------

// x (f32 [N,256]) -> bf16, pad rows zeroed
__global__ __launch_bounds__(256) void xconv_kernel(const float* __restrict__ x,
                                                    unsigned short* __restrict__ Fh) {
    int id = blockIdx.x * 256 + threadIdx.x;
    if (id >= M_PAD * 64) return;
    int row = id >> 6;
    int c = (id & 63) * 4;
    float4 v = make_float4(0.f, 0.f, 0.f, 0.f);
    if (row < N_NODES) v = *(const float4*)(x + (size_t)row * 256 + c);
    ushort4 h;
    h.x = f2b(v.x); h.y = f2b(v.y); h.z = f2b(v.z); h.w = f2b(v.w);
    *(ushort4*)(Fh + (size_t)row * 256 + c) = h;
}

// W (f32 [K,512]) -> transposed hi/lo bf16 [512,K]
__global__ __launch_bounds__(128) void wconv_kernel(const float* __restrict__ W,
                                                    unsigned short* __restrict__ Th,
                                                    unsigned short* __restrict__ Tl, int K) {
    int n = blockIdx.x;  // 0..511
    for (int k = threadIdx.x; k < K; k += 128) {
        float v = W[(size_t)k * HID + n];
        unsigned short h = f2b(v);
        Th[(size_t)n * K + k] = h;
        Tl[(size_t)n * K + k] = f2b(v - b2f(h));
    }
}

// ---------------- aggregate: gather-sum bf16 feats -> bf16 agg ----------------
// block = W/4 threads

__global__ void aggregate_kernel(const unsigned short* __restrict__ Fh,
                                 const int* __restrict__ off, const int* __restrict__ esrc,
                                 unsigned short* __restrict__ Ah, int W) {
    const int node = blockIdx.x;
    const int col = threadIdx.x * 4;
    const int beg = off[node], end = off[node + 1];
    float a0 = 0.f, a1 = 0.f, a2 = 0.f, a3 = 0.f;
    for (int i = beg; i < end; ++i) {
        const int s = esrc[i];
        ushort4 h = *(const ushort4*)(Fh + (size_t)s * W + col);
        a0 += b2f(h.x);
        a1 += b2f(h.y);
        a2 += b2f(h.z);
        a3 += b2f(h.w);
    }
    ushort4 h;
    h.x = f2b(a0); h.y = f2b(a1); h.z = f2b(a2); h.w = f2b(a3);
    *(ushort4*)(Ah + (size_t)node * W + col) = h;
}

// ---------------- MFMA GEMM over 4 (A,W) sections ----------------
// out = AH@WH1 + AH@WL1 + FH@WH2 + FH@WL2 + bias
// A/F : bf16 [M_PAD, Ks] row-major.  W* : bf16 [512, Ks] (pre-transposed).

__global__ __launch_bounds__(256) void gemm_mfma_kernel(
    const unsigned short* __restrict__ AH, const unsigned short* __restrict__ FH,
    const unsigned short* __restrict__ WH1, const unsigned short* __restrict__ WL1,
    const unsigned short* __restrict__ WH2, const unsigned short* __restrict__ WL2,
    const float* __restrict__ bias, float* __restrict__ out, int Ks) {
    __shared__ unsigned short As[128 * 32];
    __shared__ unsigned short Bs[128 * 32];
    const int bm = blockIdx.y * 128;
    const int bn = blockIdx.x * 128;
    const int tid = threadIdx.x;
    const int l = tid & 63;
    const int w = tid >> 6;
    const int wr = (w >> 1) * 64;
    const int wc = (w & 1) * 64;

    f32x4 acc[4][4];
#pragma unroll
    for (int m = 0; m < 4; ++m)
#pragma unroll
        for (int n = 0; n < 4; ++n) acc[m][n] = (f32x4){0.f, 0.f, 0.f, 0.f};

    const int arow = l >> 2;
    const int acol = (l & 3) * 8;
    const int ktiles = Ks >> 5;

    for (int s = 0; s < 4; ++s) {
        const unsigned short* Ap = (s < 2) ? AH : FH;
        const unsigned short* Wp = (s == 0) ? WH1 : (s == 1) ? WL1 : (s == 2) ? WH2 : WL2;
        for (int kt = 0; kt < ktiles; ++kt) {
            const int kb = kt << 5;
#pragma unroll
            for (int i = 0; i < 2; ++i) {
                const int c = w * 2 + i;  // 16-row chunk, 0..7
                const unsigned short* ga = Ap + (size_t)(bm + c * 16 + arow) * Ks + kb + acol;
                const unsigned short* gw = Wp + (size_t)(bn + c * 16 + arow) * Ks + kb + acol;
                __builtin_amdgcn_global_load_lds(
                    (const __attribute__((address_space(1))) void*)ga,
                    (__attribute__((address_space(3))) void*)&As[c * 512], 16, 0, 0);
                __builtin_amdgcn_global_load_lds(
                    (const __attribute__((address_space(1))) void*)gw,
                    (__attribute__((address_space(3))) void*)&Bs[c * 512], 16, 0, 0);
            }
            __syncthreads();

            bf16x8 af[4], wf[4];
#pragma unroll
            for (int m = 0; m < 4; ++m)
                af[m] = *(const bf16x8*)&As[(wr + m * 16 + (l & 15)) * 32 + (l >> 4) * 8];
#pragma unroll
            for (int n = 0; n < 4; ++n)
                wf[n] = *(const bf16x8*)&Bs[(wc + n * 16 + (l & 15)) * 32 + (l >> 4) * 8];
#pragma unroll
            for (int m = 0; m < 4; ++m)
#pragma unroll
                for (int n = 0; n < 4; ++n)
                    acc[m][n] = __builtin_amdgcn_mfma_f32_16x16x32_bf16(af[m], wf[n], acc[m][n], 0, 0, 0);
            __syncthreads();
        }
    }

    const int r0 = bm + wr + (l >> 4) * 4;
    const int c0 = bn + wc + (l & 15);
#pragma unroll
    for (int n = 0; n < 4; ++n) {
        const float bv = bias[c0 + n * 16];
#pragma unroll
        for (int m = 0; m < 4; ++m) {
#pragma unroll
            for (int j = 0; j < 4; ++j) {
                int gr = r0 + m * 16 + j;
                if (gr < N_NODES)
                    out[(size_t)gr * HID + c0 + n * 16] = acc[m][n][j] + bv;
            }
        }
    }
}

// ---------------- row L2-normalize + ELU ----------------

template <int FINAL>
__global__ __launch_bounds__(128) void norm_elu_kernel(const float* __restrict__ in,
                                                       float* __restrict__ outF,
                                                       unsigned short* __restrict__ Fh) {
    const int row = blockIdx.x;
    const int t = threadIdx.x;
    float4 v = *(const float4*)(in + (size_t)row * HID + t * 4);
    float ss = v.x * v.x + v.y * v.y + v.z * v.z + v.w * v.w;
#pragma unroll
    for (int o = 32; o > 0; o >>= 1) ss += __shfl_down(ss, o);
    __shared__ float w0, w1;
    if (t == 0) w0 = ss;
    if (t == 64) w1 = ss;
    __syncthreads();
    float inv = 1.f / fmaxf(sqrtf(w0 + w1), 1e-12f);
    v.x *= inv; v.y *= inv; v.z *= inv; v.w *= inv;
    v.x = v.x > 0.f ? v.x : expm1f(v.x);
    v.y = v.y > 0.f ? v.y : expm1f(v.y);
    v.z = v.z > 0.f ? v.z : expm1f(v.z);
    v.w = v.w > 0.f ? v.w : expm1f(v.w);
    if (FINAL) {
        *(float4*)(outF + (size_t)row * HID + t * 4) = v;
    } else {
        ushort4 h;
        h.x = f2b(v.x); h.y = f2b(v.y); h.z = f2b(v.z); h.w = f2b(v.w);
        *(ushort4*)(Fh + (size_t)row * HID + t * 4) = h;
    }
}

// ---------------- launch ----------------

extern "C" void kernel_launch(void* const* d_in, const int* in_sizes, int n_in,
                              void* d_out, int out_size, void* d_ws, size_t ws_size,
                              hipStream_t stream) {
    const float* x    = (const float*)d_in[0];
    const void*  eidx = d_in[1];
    const float* Wl0 = (const float*)d_in[2];
    const float* bl0 = (const float*)d_in[3];
    const float* Wr0 = (const float*)d_in[4];
    const float* Wl1 = (const float*)d_in[5];
    const float* bl1 = (const float*)d_in[6];
    const float* Wr1 = (const float*)d_in[7];
    const float* Wl2 = (const float*)d_in[8];
    const float* bl2 = (const float*)d_in[9];
    const float* Wr2 = (const float*)d_in[10];
    float* outF = (float*)d_out;

    char* ws = (char*)d_ws;
    size_t o = 0;
    auto alloc = [&](size_t bytes) { void* p = ws + o; o += (bytes + 255) & ~(size_t)255; return p; };

    const size_t PLANE = (size_t)M_PAD * 512 * 2;  // 51.25 MB
    unsigned short* FhB = (unsigned short*)alloc(PLANE);
    unsigned short* AhB = (unsigned short*)alloc(PLANE);

    unsigned short* Wl0tH = (unsigned short*)alloc(512 * 256 * 2);
    unsigned short* Wl0tL = (unsigned short*)alloc(512 * 256 * 2);
    unsigned short* Wr0tH = (unsigned short*)alloc(512 * 256 * 2);
    unsigned short* Wr0tL = (unsigned short*)alloc(512 * 256 * 2);
    unsigned short* Wl1tH = (unsigned short*)alloc(512 * 512 * 2);
    unsigned short* Wl1tL = (unsigned short*)alloc(512 * 512 * 2);
    unsigned short* Wr1tH = (unsigned short*)alloc(512 * 512 * 2);
    unsigned short* Wr1tL = (unsigned short*)alloc(512 * 512 * 2);
    unsigned short* Wl2tH = (unsigned short*)alloc(512 * 512 * 2);
    unsigned short* Wl2tL = (unsigned short*)alloc(512 * 512 * 2);
    unsigned short* Wr2tH = (unsigned short*)alloc(512 * 512 * 2);
    unsigned short* Wr2tL = (unsigned short*)alloc(512 * 512 * 2);

    // counts and cursor MUST be one contiguous block: zero_kernel clears
    // 2*N_NODES ints in one shot (R2/R3 crash: 256B alloc rounding left the
    // tail of a separately-alloc'd cursor poisoned -> giant atomicAdd pos ->
    // OOB edge_src writes -> GPU fault).
    int* counts   = (int*)alloc((size_t)2 * N_NODES * 4);
    int* cursor   = counts + N_NODES;
    int* offsets  = (int*)alloc((size_t)(N_NODES + 1) * 4);
    int* edge_src = (int*)alloc((size_t)N_EDGES * 4);
    int* flag     = (int*)alloc(256);

    // ---- CSR build ----
    zero_kernel<<<(2 * N_NODES + 255) / 256, 256, 0, stream>>>(counts, 2 * N_NODES);
    detect_kernel<<<1, 64, 0, stream>>>((const int*)eidx, flag);
    hist_kernel<<<(N_EDGES + 255) / 256, 256, 0, stream>>>(eidx, flag, counts);
    scan_kernel<<<1, 1024, 0, stream>>>(counts, offsets);
    fill_kernel<<<(N_EDGES + 255) / 256, 256, 0, stream>>>(eidx, flag, offsets, cursor, edge_src);

    // ---- conversions ----
    xconv_kernel<<<(M_PAD * 64 + 255) / 256, 256, 0, stream>>>(x, FhB);
    wconv_kernel<<<512, 128, 0, stream>>>(Wl0, Wl0tH, Wl0tL, 256);
    wconv_kernel<<<512, 128, 0, stream>>>(Wr0, Wr0tH, Wr0tL, 256);
    wconv_kernel<<<512, 128, 0, stream>>>(Wl1, Wl1tH, Wl1tL, 512);
    wconv_kernel<<<512, 128, 0, stream>>>(Wr1, Wr1tH, Wr1tL, 512);
    wconv_kernel<<<512, 128, 0, stream>>>(Wl2, Wl2tH, Wl2tL, 512);
    wconv_kernel<<<512, 128, 0, stream>>>(Wr2, Wr2tH, Wr2tL, 512);

    dim3 ggrid(4, M_PAD / 128);  // (512/128, 391)

    // layer 1 (feat width 256)
    aggregate_kernel<<<N_NODES, 64, 0, stream>>>(FhB, offsets, edge_src, AhB, 256);
    gemm_mfma_kernel<<<ggrid, 256, 0, stream>>>(AhB, FhB,
                                                Wl0tH, Wl0tL, Wr0tH, Wr0tL, bl0, outF, 256);
    norm_elu_kernel<0><<<N_NODES, 128, 0, stream>>>(outF, nullptr, FhB);

    // layer 2 (feat width 512)
    aggregate_kernel<<<N_NODES, 128, 0, stream>>>(FhB, offsets, edge_src, AhB, 512);
    gemm_mfma_kernel<<<ggrid, 256, 0, stream>>>(AhB, FhB,
                                                Wl1tH, Wl1tL, Wr1tH, Wr1tL, bl1, outF, 512);
    norm_elu_kernel<0><<<N_NODES, 128, 0, stream>>>(outF, nullptr, FhB);

    // layer 3 (feat width 512)
    aggregate_kernel<<<N_NODES, 128, 0, stream>>>(FhB, offsets, edge_src, AhB, 512);
    gemm_mfma_kernel<<<ggrid, 256, 0, stream>>>(AhB, FhB,
                                                Wl2tH, Wl2tL, Wr2tH, Wr2tL, bl2, outF, 512);
    norm_elu_kernel<1><<<N_NODES, 128, 0, stream>>>(outF, outF, nullptr);

    (void)in_sizes; (void)n_in; (void)out_size; (void)ws_size;
}

// Round 5
// 983.056 us; speedup vs baseline: 2.8334x; 1.0487x over previous
//
#include <hip/hip_runtime.h>
#include <math.h>

#define N_NODES 50000
#define M_PAD   50048   // 391 * 128
#define N_EDGES 800000
#define HID 512

typedef short bf16x8 __attribute__((ext_vector_type(8)));
typedef float f32x4  __attribute__((ext_vector_type(4)));

__device__ inline float b2f(unsigned short u) {
    union { unsigned int i; float f; } v; v.i = ((unsigned int)u) << 16; return v.f;
}
__device__ inline unsigned short f2b(float f) {
    union { float f; unsigned int i; } v; v.f = f;
    unsigned int r = v.i + 0x7FFFu + ((v.i >> 16) & 1u);
    return (unsigned short)(r >> 16);
}

// ---------------- CSR build ----------------

__global__ void zero_kernel(int* __restrict__ p, int n) {
    int i = blockIdx.x * blockDim.x + threadIdx.x;
    if (i < n) p[i] = 0;
}

__global__ void detect_kernel(const int* __restrict__ e, int* __restrict__ flag) {
    if (blockIdx.x == 0 && threadIdx.x == 0) {
        int is64 = 1;
        for (int i = 0; i < 16; ++i)
            if (e[2 * i + 1] != 0) is64 = 0;
        *flag = is64;
    }
}

__global__ void hist_kernel(const void* __restrict__ eidx, const int* __restrict__ flag,
                            int* __restrict__ counts) {
    int e = blockIdx.x * blockDim.x + threadIdx.x;
    if (e >= N_EDGES) return;
    int is64 = *flag;
    int d;
    if (is64) d = (int)((const long long*)eidx)[N_EDGES + e];
    else      d = ((const int*)eidx)[N_EDGES + e];
    atomicAdd(&counts[d], 1);
}

__global__ __launch_bounds__(1024) void scan_kernel(const int* __restrict__ counts,
                                                    int* __restrict__ offsets) {
    __shared__ int sums[1024];
    int t = threadIdx.x;
    const int CH = (N_NODES + 1023) / 1024;  // 49
    int lo = t * CH;
    int hi = min(lo + CH, N_NODES);
    int s = 0;
    for (int i = lo; i < hi; ++i) s += counts[i];
    sums[t] = s;
    __syncthreads();
    for (int off = 1; off < 1024; off <<= 1) {
        int v = 0;
        if (t >= off) v = sums[t - off];
        __syncthreads();
        sums[t] += v;
        __syncthreads();
    }
    int excl = (t == 0) ? 0 : sums[t - 1];
    for (int i = lo; i < hi; ++i) { offsets[i] = excl; excl += counts[i]; }
    if (t == 1023) offsets[N_NODES] = excl;
}

__global__ void fill_kernel(const void* __restrict__ eidx, const int* __restrict__ flag,
                            const int* __restrict__ offsets, int* __restrict__ cursor,
                            int* __restrict__ edge_src) {
    int e = blockIdx.x * blockDim.x + threadIdx.x;
    if (e >= N_EDGES) return;
    int is64 = *flag;
    int s, d;
    if (is64) {
        const long long* p = (const long long*)eidx;
        s = (int)p[e];
        d = (int)p[N_EDGES + e];
    } else {
        const int* p = (const int*)eidx;
        s = p[e];
        d = p[N_EDGES + e];
    }
    int pos = atomicAdd(&cursor[d], 1);
    edge_src[offsets[d] + pos] = s;
}

// ---------------- conversions ----------------

__global__ __launch_bounds__(256) void xconv_kernel(const float* __restrict__ x,
                                                    unsigned short* __restrict__ Fh) {
    int id = blockIdx.x * 256 + threadIdx.x;
    if (id >= M_PAD * 64) return;
    int row = id >> 6;
    int c = (id & 63) * 4;
    float4 v = make_float4(0.f, 0.f, 0.f, 0.f);
    if (row < N_NODES) v = *(const float4*)(x + (size_t)row * 256 + c);
    ushort4 h;
    h.x = f2b(v.x); h.y = f2b(v.y); h.z = f2b(v.z); h.w = f2b(v.w);
    *(ushort4*)(Fh + (size_t)row * 256 + c) = h;
}

// W (f32 [K,512]) -> transposed hi/lo bf16 [512,K]
__global__ __launch_bounds__(128) void wconv_kernel(const float* __restrict__ W,
                                                    unsigned short* __restrict__ Th,
                                                    unsigned short* __restrict__ Tl, int K) {
    int n = blockIdx.x;  // 0..511
    for (int k = threadIdx.x; k < K; k += 128) {
        float v = W[(size_t)k * HID + n];
        unsigned short h = f2b(v);
        Th[(size_t)n * K + k] = h;
        Tl[(size_t)n * K + k] = f2b(v - b2f(h));
    }
}

// ---------------- aggregate ----------------

__global__ void aggregate_kernel(const unsigned short* __restrict__ Fh,
                                 const int* __restrict__ off, const int* __restrict__ esrc,
                                 unsigned short* __restrict__ Ah, int W) {
    const int node = blockIdx.x;
    const int col = threadIdx.x * 4;
    const int beg = off[node], end = off[node + 1];
    float a0 = 0.f, a1 = 0.f, a2 = 0.f, a3 = 0.f;
    for (int i = beg; i < end; ++i) {
        const int s = esrc[i];
        ushort4 h = *(const ushort4*)(Fh + (size_t)s * W + col);
        a0 += b2f(h.x);
        a1 += b2f(h.y);
        a2 += b2f(h.z);
        a3 += b2f(h.w);
    }
    ushort4 h;
    h.x = f2b(a0); h.y = f2b(a1); h.z = f2b(a2); h.w = f2b(a3);
    *(ushort4*)(Ah + (size_t)node * W + col) = h;
}

// ---------------- single-pass MFMA GEMM ----------------
// out = AH@(WH1+WL1) + FH@(WH2+WL2) + bias, all 4 products accumulated in the
// same fp32 acc within ONE k-loop: per k-tile stage 6 tiles {A,F,WH1,WL1,WH2,WL2}
// (48 KB LDS) and run 64 MFMAs between one barrier pair (was 16).
// A/F : bf16 [M_PAD, Ks] row-major.  W* : bf16 [512, Ks] (pre-transposed).

__global__ __launch_bounds__(256) void gemm_mfma_kernel(
    const unsigned short* __restrict__ AH, const unsigned short* __restrict__ FH,
    const unsigned short* __restrict__ WH1, const unsigned short* __restrict__ WL1,
    const unsigned short* __restrict__ WH2, const unsigned short* __restrict__ WL2,
    const float* __restrict__ bias, float* __restrict__ out, int Ks) {
    __shared__ unsigned short S[6 * 4096];  // 6 tiles of 128x32 bf16 = 48 KB
    const int bm = blockIdx.y * 128;
    const int bn = blockIdx.x * 128;
    const int tid = threadIdx.x;
    const int l = tid & 63;
    const int w = tid >> 6;
    const int wr = (w >> 1) * 64;
    const int wc = (w & 1) * 64;

    f32x4 acc[4][4];
#pragma unroll
    for (int m = 0; m < 4; ++m)
#pragma unroll
        for (int n = 0; n < 4; ++n) acc[m][n] = (f32x4){0.f, 0.f, 0.f, 0.f};

    const int arow = l >> 2;        // 0..15 within a 16-row chunk
    const int acol = (l & 3) * 8;   // bf16 col within BK=32

    // Precompute the 12 staging (global ptr, LDS offset) pairs per thread.
    // Static unroll keeps gptr[] in registers (runtime-indexed arrays spill).
    const unsigned short* gptr[12];
    unsigned int loff[12];
#pragma unroll
    for (int t = 0; t < 12; ++t) {
        const int g = w * 12 + t;   // 0..47
        const int tile = g >> 3;    // 0..5
        const int c = g & 7;        // 16-row chunk within tile
        const unsigned short* bp =
            (tile == 0) ? AH : (tile == 1) ? FH :
            (tile == 2) ? WH1 : (tile == 3) ? WL1 :
            (tile == 4) ? WH2 : WL2;
        const int rb = ((tile < 2) ? bm : bn) + c * 16 + arow;
        gptr[t] = bp + (size_t)rb * Ks + acol;
        loff[t] = tile * 4096 + c * 512;
    }

    const int aoff = (wr + (l & 15)) * 32 + (l >> 4) * 8;
    const int woff = (wc + (l & 15)) * 32 + (l >> 4) * 8;
    const int ktiles = Ks >> 5;

    for (int kt = 0; kt < ktiles; ++kt) {
#pragma unroll
        for (int t = 0; t < 12; ++t) {
            __builtin_amdgcn_global_load_lds(
                (const __attribute__((address_space(1))) void*)gptr[t],
                (__attribute__((address_space(3))) void*)&S[loff[t]], 16, 0, 0);
            gptr[t] += 32;
        }
        __syncthreads();

        bf16x8 af[4], ff[4];
#pragma unroll
        for (int m = 0; m < 4; ++m) {
            af[m] = *(const bf16x8*)&S[aoff + m * 512];
            ff[m] = *(const bf16x8*)&S[4096 + aoff + m * 512];
        }
#pragma unroll
        for (int p = 0; p < 4; ++p) {
            bf16x8 wf[4];
#pragma unroll
            for (int n = 0; n < 4; ++n)
                wf[n] = *(const bf16x8*)&S[(2 + p) * 4096 + woff + n * 512];
#pragma unroll
            for (int m = 0; m < 4; ++m)
#pragma unroll
                for (int n = 0; n < 4; ++n)
                    acc[m][n] = __builtin_amdgcn_mfma_f32_16x16x32_bf16(
                        (p < 2) ? af[m] : ff[m], wf[n], acc[m][n], 0, 0, 0);
        }
        __syncthreads();
    }

    const int r0 = bm + wr + (l >> 4) * 4;
    const int c0 = bn + wc + (l & 15);
#pragma unroll
    for (int n = 0; n < 4; ++n) {
        const float bv = bias[c0 + n * 16];
#pragma unroll
        for (int m = 0; m < 4; ++m) {
#pragma unroll
            for (int j = 0; j < 4; ++j) {
                int gr = r0 + m * 16 + j;
                if (gr < N_NODES)
                    out[(size_t)gr * HID + c0 + n * 16] = acc[m][n][j] + bv;
            }
        }
    }
}

// ---------------- row L2-normalize + ELU ----------------

template <int FINAL>
__global__ __launch_bounds__(128) void norm_elu_kernel(const float* __restrict__ in,
                                                       float* __restrict__ outF,
                                                       unsigned short* __restrict__ Fh) {
    const int row = blockIdx.x;
    const int t = threadIdx.x;
    float4 v = *(const float4*)(in + (size_t)row * HID + t * 4);
    float ss = v.x * v.x + v.y * v.y + v.z * v.z + v.w * v.w;
#pragma unroll
    for (int o = 32; o > 0; o >>= 1) ss += __shfl_down(ss, o);
    __shared__ float w0, w1;
    if (t == 0) w0 = ss;
    if (t == 64) w1 = ss;
    __syncthreads();
    float inv = 1.f / fmaxf(sqrtf(w0 + w1), 1e-12f);
    v.x *= inv; v.y *= inv; v.z *= inv; v.w *= inv;
    v.x = v.x > 0.f ? v.x : expm1f(v.x);
    v.y = v.y > 0.f ? v.y : expm1f(v.y);
    v.z = v.z > 0.f ? v.z : expm1f(v.z);
    v.w = v.w > 0.f ? v.w : expm1f(v.w);
    if (FINAL) {
        *(float4*)(outF + (size_t)row * HID + t * 4) = v;
    } else {
        ushort4 h;
        h.x = f2b(v.x); h.y = f2b(v.y); h.z = f2b(v.z); h.w = f2b(v.w);
        *(ushort4*)(Fh + (size_t)row * HID + t * 4) = h;
    }
}

// ---------------- launch ----------------

extern "C" void kernel_launch(void* const* d_in, const int* in_sizes, int n_in,
                              void* d_out, int out_size, void* d_ws, size_t ws_size,
                              hipStream_t stream) {
    const float* x    = (const float*)d_in[0];
    const void*  eidx = d_in[1];
    const float* Wl0 = (const float*)d_in[2];
    const float* bl0 = (const float*)d_in[3];
    const float* Wr0 = (const float*)d_in[4];
    const float* Wl1 = (const float*)d_in[5];
    const float* bl1 = (const float*)d_in[6];
    const float* Wr1 = (const float*)d_in[7];
    const float* Wl2 = (const float*)d_in[8];
    const float* bl2 = (const float*)d_in[9];
    const float* Wr2 = (const float*)d_in[10];
    float* outF = (float*)d_out;

    char* ws = (char*)d_ws;
    size_t o = 0;
    auto alloc = [&](size_t bytes) { void* p = ws + o; o += (bytes + 255) & ~(size_t)255; return p; };

    const size_t PLANE = (size_t)M_PAD * 512 * 2;  // 51.25 MB
    unsigned short* FhB = (unsigned short*)alloc(PLANE);
    unsigned short* AhB = (unsigned short*)alloc(PLANE);

    unsigned short* Wl0tH = (unsigned short*)alloc(512 * 256 * 2);
    unsigned short* Wl0tL = (unsigned short*)alloc(512 * 256 * 2);
    unsigned short* Wr0tH = (unsigned short*)alloc(512 * 256 * 2);
    unsigned short* Wr0tL = (unsigned short*)alloc(512 * 256 * 2);
    unsigned short* Wl1tH = (unsigned short*)alloc(512 * 512 * 2);
    unsigned short* Wl1tL = (unsigned short*)alloc(512 * 512 * 2);
    unsigned short* Wr1tH = (unsigned short*)alloc(512 * 512 * 2);
    unsigned short* Wr1tL = (unsigned short*)alloc(512 * 512 * 2);
    unsigned short* Wl2tH = (unsigned short*)alloc(512 * 512 * 2);
    unsigned short* Wl2tL = (unsigned short*)alloc(512 * 512 * 2);
    unsigned short* Wr2tH = (unsigned short*)alloc(512 * 512 * 2);
    unsigned short* Wr2tL = (unsigned short*)alloc(512 * 512 * 2);

    // counts and cursor MUST be one contiguous block: zero_kernel clears
    // 2*N_NODES ints in one shot (R2/R3 crash: 256B alloc rounding left the
    // tail of a separately-alloc'd cursor poisoned -> giant atomicAdd pos ->
    // OOB edge_src writes -> GPU fault).
    int* counts   = (int*)alloc((size_t)2 * N_NODES * 4);
    int* cursor   = counts + N_NODES;
    int* offsets  = (int*)alloc((size_t)(N_NODES + 1) * 4);
    int* edge_src = (int*)alloc((size_t)N_EDGES * 4);
    int* flag     = (int*)alloc(256);

    // ---- CSR build ----
    zero_kernel<<<(2 * N_NODES + 255) / 256, 256, 0, stream>>>(counts, 2 * N_NODES);
    detect_kernel<<<1, 64, 0, stream>>>((const int*)eidx, flag);
    hist_kernel<<<(N_EDGES + 255) / 256, 256, 0, stream>>>(eidx, flag, counts);
    scan_kernel<<<1, 1024, 0, stream>>>(counts, offsets);
    fill_kernel<<<(N_EDGES + 255) / 256, 256, 0, stream>>>(eidx, flag, offsets, cursor, edge_src);

    // ---- conversions ----
    xconv_kernel<<<(M_PAD * 64 + 255) / 256, 256, 0, stream>>>(x, FhB);
    wconv_kernel<<<512, 128, 0, stream>>>(Wl0, Wl0tH, Wl0tL, 256);
    wconv_kernel<<<512, 128, 0, stream>>>(Wr0, Wr0tH, Wr0tL, 256);
    wconv_kernel<<<512, 128, 0, stream>>>(Wl1, Wl1tH, Wl1tL, 512);
    wconv_kernel<<<512, 128, 0, stream>>>(Wr1, Wr1tH, Wr1tL, 512);
    wconv_kernel<<<512, 128, 0, stream>>>(Wl2, Wl2tH, Wl2tL, 512);
    wconv_kernel<<<512, 128, 0, stream>>>(Wr2, Wr2tH, Wr2tL, 512);

    dim3 ggrid(4, M_PAD / 128);  // (512/128, 391)

    // layer 1 (feat width 256)
    aggregate_kernel<<<N_NODES, 64, 0, stream>>>(FhB, offsets, edge_src, AhB, 256);
    gemm_mfma_kernel<<<ggrid, 256, 0, stream>>>(AhB, FhB,
                                                Wl0tH, Wl0tL, Wr0tH, Wr0tL, bl0, outF, 256);
    norm_elu_kernel<0><<<N_NODES, 128, 0, stream>>>(outF, nullptr, FhB);

    // layer 2 (feat width 512)
    aggregate_kernel<<<N_NODES, 128, 0, stream>>>(FhB, offsets, edge_src, AhB, 512);
    gemm_mfma_kernel<<<ggrid, 256, 0, stream>>>(AhB, FhB,
                                                Wl1tH, Wl1tL, Wr1tH, Wr1tL, bl1, outF, 512);
    norm_elu_kernel<0><<<N_NODES, 128, 0, stream>>>(outF, nullptr, FhB);

    // layer 3 (feat width 512)
    aggregate_kernel<<<N_NODES, 128, 0, stream>>>(FhB, offsets, edge_src, AhB, 512);
    gemm_mfma_kernel<<<ggrid, 256, 0, stream>>>(AhB, FhB,
                                                Wl2tH, Wl2tL, Wr2tH, Wr2tL, bl2, outF, 512);
    norm_elu_kernel<1><<<N_NODES, 128, 0, stream>>>(outF, outF, nullptr);

    (void)in_sizes; (void)n_in; (void)out_size; (void)ws_size;
}

// Round 6
// 862.499 us; speedup vs baseline: 3.2294x; 1.1398x over previous
//
#include <hip/hip_runtime.h>
#include <math.h>

#define N_NODES 50000
#define M_PAD   50048   // 391 * 128
#define N_EDGES 800000
#define HID 512

typedef short bf16x8 __attribute__((ext_vector_type(8)));
typedef float f32x4  __attribute__((ext_vector_type(4)));
typedef unsigned short u16x4 __attribute__((ext_vector_type(4)));

__device__ inline float b2f(unsigned short u) {
    union { unsigned int i; float f; } v; v.i = ((unsigned int)u) << 16; return v.f;
}
__device__ inline unsigned short f2b(float f) {
    union { float f; unsigned int i; } v; v.f = f;
    unsigned int r = v.i + 0x7FFFu + ((v.i >> 16) & 1u);
    return (unsigned short)(r >> 16);
}

// ---------------- CSR build ----------------

__global__ void zero_kernel(int* __restrict__ p, int n) {
    int i = blockIdx.x * blockDim.x + threadIdx.x;
    if (i < n) p[i] = 0;
}

__global__ void detect_kernel(const int* __restrict__ e, int* __restrict__ flag) {
    if (blockIdx.x == 0 && threadIdx.x == 0) {
        int is64 = 1;
        for (int i = 0; i < 16; ++i)
            if (e[2 * i + 1] != 0) is64 = 0;
        *flag = is64;
    }
}

__global__ void hist_kernel(const void* __restrict__ eidx, const int* __restrict__ flag,
                            int* __restrict__ counts) {
    int e = blockIdx.x * blockDim.x + threadIdx.x;
    if (e >= N_EDGES) return;
    int is64 = *flag;
    int d;
    if (is64) d = (int)((const long long*)eidx)[N_EDGES + e];
    else      d = ((const int*)eidx)[N_EDGES + e];
    atomicAdd(&counts[d], 1);
}

__global__ __launch_bounds__(1024) void scan_kernel(const int* __restrict__ counts,
                                                    int* __restrict__ offsets) {
    __shared__ int sums[1024];
    int t = threadIdx.x;
    const int CH = (N_NODES + 1023) / 1024;  // 49
    int lo = t * CH;
    int hi = min(lo + CH, N_NODES);
    int s = 0;
    for (int i = lo; i < hi; ++i) s += counts[i];
    sums[t] = s;
    __syncthreads();
    for (int off = 1; off < 1024; off <<= 1) {
        int v = 0;
        if (t >= off) v = sums[t - off];
        __syncthreads();
        sums[t] += v;
        __syncthreads();
    }
    int excl = (t == 0) ? 0 : sums[t - 1];
    for (int i = lo; i < hi; ++i) { offsets[i] = excl; excl += counts[i]; }
    if (t == 1023) offsets[N_NODES] = excl;
}

__global__ void fill_kernel(const void* __restrict__ eidx, const int* __restrict__ flag,
                            const int* __restrict__ offsets, int* __restrict__ cursor,
                            int* __restrict__ edge_src) {
    int e = blockIdx.x * blockDim.x + threadIdx.x;
    if (e >= N_EDGES) return;
    int is64 = *flag;
    int s, d;
    if (is64) {
        const long long* p = (const long long*)eidx;
        s = (int)p[e];
        d = (int)p[N_EDGES + e];
    } else {
        const int* p = (const int*)eidx;
        s = p[e];
        d = p[N_EDGES + e];
    }
    int pos = atomicAdd(&cursor[d], 1);
    edge_src[offsets[d] + pos] = s;
}

// ---------------- conversions ----------------

__global__ __launch_bounds__(256) void xconv_kernel(const float* __restrict__ x,
                                                    unsigned short* __restrict__ Fh) {
    int id = blockIdx.x * 256 + threadIdx.x;
    if (id >= M_PAD * 64) return;
    int row = id >> 6;
    int c = (id & 63) * 4;
    float4 v = make_float4(0.f, 0.f, 0.f, 0.f);
    if (row < N_NODES) v = *(const float4*)(x + (size_t)row * 256 + c);
    ushort4 h;
    h.x = f2b(v.x); h.y = f2b(v.y); h.z = f2b(v.z); h.w = f2b(v.w);
    *(ushort4*)(Fh + (size_t)row * 256 + c) = h;
}

// W (f32 [K,512]) -> transposed bf16 [512,K]
__global__ __launch_bounds__(128) void wconv_kernel(const float* __restrict__ W,
                                                    unsigned short* __restrict__ T, int K) {
    int n = blockIdx.x;  // 0..511
    for (int k = threadIdx.x; k < K; k += 128)
        T[(size_t)n * K + k] = f2b(W[(size_t)k * HID + n]);
}

// ---------------- aggregate: wave-per-node gather-sum ----------------
// EPL = elements per lane (W = EPL*64). Lane loads its EPL-wide slice of each
// neighbor row; edge indices batch-loaded once per 64 edges, shfl-broadcast.

template <int EPL>
__global__ __launch_bounds__(256) void aggregate_kernel(const unsigned short* __restrict__ Fh,
                                                        const int* __restrict__ off,
                                                        const int* __restrict__ esrc,
                                                        unsigned short* __restrict__ Ah) {
    const int W = EPL * 64;
    const int wid = threadIdx.x >> 6;
    const int lane = threadIdx.x & 63;
    const int node = blockIdx.x * 4 + wid;
    if (node >= N_NODES) return;
    const int beg = off[node], end = off[node + 1];
    const int deg = end - beg;

    float a0[EPL], a1[EPL];
#pragma unroll
    for (int j = 0; j < EPL; ++j) { a0[j] = 0.f; a1[j] = 0.f; }

    int idxv = (beg + lane < end) ? esrc[beg + lane] : 0;
    for (int i = 0; i < deg; i += 2) {
        const int b = i & 63;
        if (b == 0 && i)
            idxv = (beg + i + lane < end) ? esrc[beg + i + lane] : 0;
        {
            const int s = __shfl(idxv, b);
            const unsigned short* r = Fh + (size_t)s * W + lane * EPL;
#pragma unroll
            for (int q = 0; q < EPL / 4; ++q) {
                u16x4 v = *(const u16x4*)(r + q * 4);
#pragma unroll
                for (int j = 0; j < 4; ++j) a0[q * 4 + j] += b2f(v[j]);
            }
        }
        if (i + 1 < deg) {
            const int s = __shfl(idxv, b + 1);
            const unsigned short* r = Fh + (size_t)s * W + lane * EPL;
#pragma unroll
            for (int q = 0; q < EPL / 4; ++q) {
                u16x4 v = *(const u16x4*)(r + q * 4);
#pragma unroll
                for (int j = 0; j < 4; ++j) a1[q * 4 + j] += b2f(v[j]);
            }
        }
    }

    unsigned short* op = Ah + (size_t)node * W + lane * EPL;
#pragma unroll
    for (int q = 0; q < EPL / 4; ++q) {
        u16x4 h;
#pragma unroll
        for (int j = 0; j < 4; ++j) h[j] = f2b(a0[q * 4 + j] + a1[q * 4 + j]);
        *(u16x4*)(op + q * 4) = h;
    }
}

// ---------------- 2-phase double-buffered MFMA GEMM ----------------
// out = A@W1 + F@W2 + bias.  A/F: bf16 [M_PAD, Ks] row-major; W1/W2: bf16
// [512, Ks] pre-transposed.  Tile 128x128, BK=32, 4 waves (64x64 each).
// Per k-iter: stage k+1 into buf^1 (wave w stages its own plane), compute
// buf k, ONE __syncthreads() (vmcnt(0)+barrier) -- staging latency hides
// under the previous iteration's ds_read+MFMA work.

__global__ __launch_bounds__(256) void gemm_mfma_kernel(
    const unsigned short* __restrict__ A, const unsigned short* __restrict__ F,
    const unsigned short* __restrict__ W1, const unsigned short* __restrict__ W2,
    const float* __restrict__ bias, float* __restrict__ out, int Ks) {
    __shared__ unsigned short S[2 * 16384];  // 64 KB: 2 buf x {A,F,W1,W2} x 128x32
    const int bm = blockIdx.y * 128;
    const int bn = blockIdx.x * 128;
    const int tid = threadIdx.x;
    const int l = tid & 63;
    const int w = tid >> 6;
    const int wr = (w >> 1) * 64;
    const int wc = (w & 1) * 64;
    const int arow = l >> 2;        // staging row within 16-row chunk
    const int acol = (l & 3) * 8;   // staging bf16 col within BK=32

    // wave w stages plane w: {A, F, W1, W2}
    const unsigned short* wsrc = (w == 0) ? A : (w == 1) ? F : (w == 2) ? W1 : W2;
    const int rb = (w < 2) ? bm : bn;
    const unsigned short* gbase = wsrc + (size_t)(rb + arow) * Ks + acol;
    const size_t cstride = (size_t)16 * Ks;

    f32x4 acc[4][4];
#pragma unroll
    for (int m = 0; m < 4; ++m)
#pragma unroll
        for (int n = 0; n < 4; ++n) acc[m][n] = (f32x4){0.f, 0.f, 0.f, 0.f};

    const int aoff = (wr + (l & 15)) * 32 + (l >> 4) * 8;
    const int woff = (wc + (l & 15)) * 32 + (l >> 4) * 8;
    const int ktiles = Ks >> 5;

    auto STAGE = [&](int buf, int kt) {
        const unsigned short* g = gbase + kt * 32;
        unsigned short* lb = &S[buf * 16384 + w * 4096];
#pragma unroll
        for (int c = 0; c < 8; ++c) {
            __builtin_amdgcn_global_load_lds(
                (const __attribute__((address_space(1))) void*)(g + (size_t)c * cstride),
                (__attribute__((address_space(3))) void*)(lb + c * 512), 16, 0, 0);
        }
    };

    STAGE(0, 0);
    __syncthreads();

    for (int kt = 0; kt < ktiles; ++kt) {
        if (kt + 1 < ktiles) STAGE((kt + 1) & 1, kt + 1);  // prefetch next tile
        const int sb = (kt & 1) * 16384;

        bf16x8 af[4], ff[4], w1f[4], w2f[4];
#pragma unroll
        for (int m = 0; m < 4; ++m) {
            af[m] = *(const bf16x8*)&S[sb + aoff + m * 512];
            ff[m] = *(const bf16x8*)&S[sb + 4096 + aoff + m * 512];
        }
#pragma unroll
        for (int n = 0; n < 4; ++n) {
            w1f[n] = *(const bf16x8*)&S[sb + 8192 + woff + n * 512];
            w2f[n] = *(const bf16x8*)&S[sb + 12288 + woff + n * 512];
        }
#pragma unroll
        for (int m = 0; m < 4; ++m)
#pragma unroll
            for (int n = 0; n < 4; ++n) {
                acc[m][n] = __builtin_amdgcn_mfma_f32_16x16x32_bf16(af[m], w1f[n], acc[m][n], 0, 0, 0);
                acc[m][n] = __builtin_amdgcn_mfma_f32_16x16x32_bf16(ff[m], w2f[n], acc[m][n], 0, 0, 0);
            }
        __syncthreads();  // drains staged buf's vmcnt + protects buf we just read
    }

    const int r0 = bm + wr + (l >> 4) * 4;
    const int c0 = bn + wc + (l & 15);
#pragma unroll
    for (int n = 0; n < 4; ++n) {
        const float bv = bias[c0 + n * 16];
#pragma unroll
        for (int m = 0; m < 4; ++m) {
#pragma unroll
            for (int j = 0; j < 4; ++j) {
                int gr = r0 + m * 16 + j;
                if (gr < N_NODES)
                    out[(size_t)gr * HID + c0 + n * 16] = acc[m][n][j] + bv;
            }
        }
    }
}

// ---------------- row L2-normalize + ELU (wave-per-row) ----------------

template <int FINAL>
__global__ __launch_bounds__(256) void norm_elu_kernel(const float* __restrict__ in,
                                                       float* __restrict__ outF,
                                                       unsigned short* __restrict__ Fh) {
    const int wid = threadIdx.x >> 6;
    const int lane = threadIdx.x & 63;
    const int row = blockIdx.x * 4 + wid;
    if (row >= N_NODES) return;
    const float* p = in + (size_t)row * HID + lane * 8;
    float4 v0 = *(const float4*)p;
    float4 v1 = *(const float4*)(p + 4);
    float ss = v0.x * v0.x + v0.y * v0.y + v0.z * v0.z + v0.w * v0.w
             + v1.x * v1.x + v1.y * v1.y + v1.z * v1.z + v1.w * v1.w;
#pragma unroll
    for (int o = 32; o > 0; o >>= 1) ss += __shfl_xor(ss, o);
    float inv = 1.f / fmaxf(sqrtf(ss), 1e-12f);
    float r[8] = {v0.x, v0.y, v0.z, v0.w, v1.x, v1.y, v1.z, v1.w};
#pragma unroll
    for (int j = 0; j < 8; ++j) {
        r[j] *= inv;
        r[j] = r[j] > 0.f ? r[j] : expm1f(r[j]);
    }
    if (FINAL) {
        float* q = outF + (size_t)row * HID + lane * 8;
        *(float4*)q = make_float4(r[0], r[1], r[2], r[3]);
        *(float4*)(q + 4) = make_float4(r[4], r[5], r[6], r[7]);
    } else {
        unsigned short* q = Fh + (size_t)row * HID + lane * 8;
        u16x4 h0, h1;
#pragma unroll
        for (int j = 0; j < 4; ++j) { h0[j] = f2b(r[j]); h1[j] = f2b(r[4 + j]); }
        *(u16x4*)q = h0;
        *(u16x4*)(q + 4) = h1;
    }
}

// ---------------- launch ----------------

extern "C" void kernel_launch(void* const* d_in, const int* in_sizes, int n_in,
                              void* d_out, int out_size, void* d_ws, size_t ws_size,
                              hipStream_t stream) {
    const float* x    = (const float*)d_in[0];
    const void*  eidx = d_in[1];
    const float* Wl0 = (const float*)d_in[2];
    const float* bl0 = (const float*)d_in[3];
    const float* Wr0 = (const float*)d_in[4];
    const float* Wl1 = (const float*)d_in[5];
    const float* bl1 = (const float*)d_in[6];
    const float* Wr1 = (const float*)d_in[7];
    const float* Wl2 = (const float*)d_in[8];
    const float* bl2 = (const float*)d_in[9];
    const float* Wr2 = (const float*)d_in[10];
    float* outF = (float*)d_out;

    char* ws = (char*)d_ws;
    size_t o = 0;
    auto alloc = [&](size_t bytes) { void* p = ws + o; o += (bytes + 255) & ~(size_t)255; return p; };

    const size_t PLANE = (size_t)M_PAD * 512 * 2;  // 51.25 MB
    unsigned short* FhB = (unsigned short*)alloc(PLANE);
    unsigned short* AhB = (unsigned short*)alloc(PLANE);

    unsigned short* Wl0t = (unsigned short*)alloc(512 * 256 * 2);
    unsigned short* Wr0t = (unsigned short*)alloc(512 * 256 * 2);
    unsigned short* Wl1t = (unsigned short*)alloc(512 * 512 * 2);
    unsigned short* Wr1t = (unsigned short*)alloc(512 * 512 * 2);
    unsigned short* Wl2t = (unsigned short*)alloc(512 * 512 * 2);
    unsigned short* Wr2t = (unsigned short*)alloc(512 * 512 * 2);

    // counts and cursor MUST be one contiguous block: zero_kernel clears
    // 2*N_NODES ints in one shot (R2/R3 crash: 256B alloc rounding left the
    // tail of a separately-alloc'd cursor poisoned -> giant atomicAdd pos ->
    // OOB edge_src writes -> GPU fault).
    int* counts   = (int*)alloc((size_t)2 * N_NODES * 4);
    int* cursor   = counts + N_NODES;
    int* offsets  = (int*)alloc((size_t)(N_NODES + 1) * 4);
    int* edge_src = (int*)alloc((size_t)N_EDGES * 4);
    int* flag     = (int*)alloc(256);

    // ---- CSR build ----
    zero_kernel<<<(2 * N_NODES + 255) / 256, 256, 0, stream>>>(counts, 2 * N_NODES);
    detect_kernel<<<1, 64, 0, stream>>>((const int*)eidx, flag);
    hist_kernel<<<(N_EDGES + 255) / 256, 256, 0, stream>>>(eidx, flag, counts);
    scan_kernel<<<1, 1024, 0, stream>>>(counts, offsets);
    fill_kernel<<<(N_EDGES + 255) / 256, 256, 0, stream>>>(eidx, flag, offsets, cursor, edge_src);

    // ---- conversions ----
    xconv_kernel<<<(M_PAD * 64 + 255) / 256, 256, 0, stream>>>(x, FhB);
    wconv_kernel<<<512, 128, 0, stream>>>(Wl0, Wl0t, 256);
    wconv_kernel<<<512, 128, 0, stream>>>(Wr0, Wr0t, 256);
    wconv_kernel<<<512, 128, 0, stream>>>(Wl1, Wl1t, 512);
    wconv_kernel<<<512, 128, 0, stream>>>(Wr1, Wr1t, 512);
    wconv_kernel<<<512, 128, 0, stream>>>(Wl2, Wl2t, 512);
    wconv_kernel<<<512, 128, 0, stream>>>(Wr2, Wr2t, 512);

    dim3 ggrid(4, M_PAD / 128);      // (512/128, 391)
    const int ngrid = (N_NODES + 3) / 4;  // 4 rows per 256-block

    // layer 1 (feat width 256)
    aggregate_kernel<4><<<ngrid, 256, 0, stream>>>(FhB, offsets, edge_src, AhB);
    gemm_mfma_kernel<<<ggrid, 256, 0, stream>>>(AhB, FhB, Wl0t, Wr0t, bl0, outF, 256);
    norm_elu_kernel<0><<<ngrid, 256, 0, stream>>>(outF, nullptr, FhB);

    // layer 2 (feat width 512)
    aggregate_kernel<8><<<ngrid, 256, 0, stream>>>(FhB, offsets, edge_src, AhB);
    gemm_mfma_kernel<<<ggrid, 256, 0, stream>>>(AhB, FhB, Wl1t, Wr1t, bl1, outF, 512);
    norm_elu_kernel<0><<<ngrid, 256, 0, stream>>>(outF, nullptr, FhB);

    // layer 3 (feat width 512)
    aggregate_kernel<8><<<ngrid, 256, 0, stream>>>(FhB, offsets, edge_src, AhB);
    gemm_mfma_kernel<<<ggrid, 256, 0, stream>>>(AhB, FhB, Wl2t, Wr2t, bl2, outF, 512);
    norm_elu_kernel<1><<<ngrid, 256, 0, stream>>>(outF, outF, nullptr);

    (void)in_sizes; (void)n_in; (void)out_size; (void)ws_size;
}

// Round 7
// 809.270 us; speedup vs baseline: 3.4418x; 1.0658x over previous
//
#include <hip/hip_runtime.h>
#include <math.h>

#define N_NODES 50000
#define M_PAD   50048   // 391 * 128
#define N_EDGES 800000
#define HID 512

typedef short bf16x8 __attribute__((ext_vector_type(8)));
typedef float f32x4  __attribute__((ext_vector_type(4)));
typedef unsigned short u16x4 __attribute__((ext_vector_type(4)));

__device__ inline float b2f(unsigned short u) {
    union { unsigned int i; float f; } v; v.i = ((unsigned int)u) << 16; return v.f;
}
__device__ inline unsigned short f2b(float f) {
    union { float f; unsigned int i; } v; v.f = f;
    unsigned int r = v.i + 0x7FFFu + ((v.i >> 16) & 1u);
    return (unsigned short)(r >> 16);
}

// ---------------- CSR build ----------------

__global__ void zero_kernel(int* __restrict__ p, int n) {
    int i = blockIdx.x * blockDim.x + threadIdx.x;
    if (i < n) p[i] = 0;
}

__global__ void detect_kernel(const int* __restrict__ e, int* __restrict__ flag) {
    if (blockIdx.x == 0 && threadIdx.x == 0) {
        int is64 = 1;
        for (int i = 0; i < 16; ++i)
            if (e[2 * i + 1] != 0) is64 = 0;
        *flag = is64;
    }
}

__global__ void hist_kernel(const void* __restrict__ eidx, const int* __restrict__ flag,
                            int* __restrict__ counts) {
    int e = blockIdx.x * blockDim.x + threadIdx.x;
    if (e >= N_EDGES) return;
    int is64 = *flag;
    int d;
    if (is64) d = (int)((const long long*)eidx)[N_EDGES + e];
    else      d = ((const int*)eidx)[N_EDGES + e];
    atomicAdd(&counts[d], 1);
}

__global__ __launch_bounds__(1024) void scan_kernel(const int* __restrict__ counts,
                                                    int* __restrict__ offsets) {
    __shared__ int sums[1024];
    int t = threadIdx.x;
    const int CH = (N_NODES + 1023) / 1024;  // 49
    int lo = t * CH;
    int hi = min(lo + CH, N_NODES);
    int s = 0;
    for (int i = lo; i < hi; ++i) s += counts[i];
    sums[t] = s;
    __syncthreads();
    for (int off = 1; off < 1024; off <<= 1) {
        int v = 0;
        if (t >= off) v = sums[t - off];
        __syncthreads();
        sums[t] += v;
        __syncthreads();
    }
    int excl = (t == 0) ? 0 : sums[t - 1];
    for (int i = lo; i < hi; ++i) { offsets[i] = excl; excl += counts[i]; }
    if (t == 1023) offsets[N_NODES] = excl;
}

__global__ void fill_kernel(const void* __restrict__ eidx, const int* __restrict__ flag,
                            const int* __restrict__ offsets, int* __restrict__ cursor,
                            int* __restrict__ edge_src) {
    int e = blockIdx.x * blockDim.x + threadIdx.x;
    if (e >= N_EDGES) return;
    int is64 = *flag;
    int s, d;
    if (is64) {
        const long long* p = (const long long*)eidx;
        s = (int)p[e];
        d = (int)p[N_EDGES + e];
    } else {
        const int* p = (const int*)eidx;
        s = p[e];
        d = p[N_EDGES + e];
    }
    int pos = atomicAdd(&cursor[d], 1);
    edge_src[offsets[d] + pos] = s;
}

// ---------------- conversions ----------------

// x (f32 [N,256]) -> bf16 into feat-half of Cat1 ([M][512], cols 256..512)
__global__ __launch_bounds__(256) void xconv_kernel(const float* __restrict__ x,
                                                    unsigned short* __restrict__ cat1) {
    int id = blockIdx.x * 256 + threadIdx.x;
    if (id >= M_PAD * 64) return;
    int row = id >> 6;
    int c = (id & 63) * 4;
    float4 v = make_float4(0.f, 0.f, 0.f, 0.f);
    if (row < N_NODES) v = *(const float4*)(x + (size_t)row * 256 + c);
    ushort4 h;
    h.x = f2b(v.x); h.y = f2b(v.y); h.z = f2b(v.z); h.w = f2b(v.w);
    *(ushort4*)(cat1 + (size_t)row * 512 + 256 + c) = h;
}

// W (f32 [K,512]) -> transposed bf16 into Wcat[n][off + k], row stride ktot
__global__ __launch_bounds__(128) void wconv_kernel(const float* __restrict__ W,
                                                    unsigned short* __restrict__ T,
                                                    int K, int ktot, int off) {
    int n = blockIdx.x;  // 0..511
    for (int k = threadIdx.x; k < K; k += 128)
        T[(size_t)n * ktot + off + k] = f2b(W[(size_t)k * HID + n]);
}

// ---------------- aggregate: wave-per-node gather-sum ----------------
// Feat width W = EPL*64, row stride 2W (feat is a half of the concat plane).
// Reads Fh (feat-half base), writes Ah (agg-half base), both stride 2W.

template <int EPL>
__global__ __launch_bounds__(256) void aggregate_kernel(const unsigned short* __restrict__ Fh,
                                                        const int* __restrict__ off,
                                                        const int* __restrict__ esrc,
                                                        unsigned short* __restrict__ Ah) {
    const int W = EPL * 64;
    const int STRIDE = 2 * W;
    const int wid = threadIdx.x >> 6;
    const int lane = threadIdx.x & 63;
    const int node = blockIdx.x * 4 + wid;
    if (node >= N_NODES) return;
    const int beg = off[node], end = off[node + 1];
    const int deg = end - beg;

    float a0[EPL], a1[EPL];
#pragma unroll
    for (int j = 0; j < EPL; ++j) { a0[j] = 0.f; a1[j] = 0.f; }

    int idxv = (beg + lane < end) ? esrc[beg + lane] : 0;
    for (int i = 0; i < deg; i += 2) {
        const int b = i & 63;
        if (b == 0 && i)
            idxv = (beg + i + lane < end) ? esrc[beg + i + lane] : 0;
        {
            const int s = __shfl(idxv, b);
            const unsigned short* r = Fh + (size_t)s * STRIDE + lane * EPL;
#pragma unroll
            for (int q = 0; q < EPL / 4; ++q) {
                u16x4 v = *(const u16x4*)(r + q * 4);
#pragma unroll
                for (int j = 0; j < 4; ++j) a0[q * 4 + j] += b2f(v[j]);
            }
        }
        if (i + 1 < deg) {
            const int s = __shfl(idxv, b + 1);
            const unsigned short* r = Fh + (size_t)s * STRIDE + lane * EPL;
#pragma unroll
            for (int q = 0; q < EPL / 4; ++q) {
                u16x4 v = *(const u16x4*)(r + q * 4);
#pragma unroll
                for (int j = 0; j < 4; ++j) a1[q * 4 + j] += b2f(v[j]);
            }
        }
    }

    unsigned short* op = Ah + (size_t)node * STRIDE + lane * EPL;
#pragma unroll
    for (int q = 0; q < EPL / 4; ++q) {
        u16x4 h;
#pragma unroll
        for (int j = 0; j < 4; ++j) h[j] = f2b(a0[q * 4 + j] + a1[q * 4 + j]);
        *(u16x4*)(op + q * 4) = h;
    }
}

// ---------------- concat-K 2-phase double-buffered MFMA GEMM ----------------
// out = Acat @ Bcat^T + bias, Acat: bf16 [M_PAD][K] (K = 2*din, agg|feat),
// Bcat: bf16 [512][K] (W1^T|W2^T).  Tile 128x128, BK=32, 4 waves, 2 planes x
// 2 bufs = 32 KB LDS -> 5 blocks/CU.  One __syncthreads (vmcnt drain) per
// k-iter; prefetch of k+1 issued before compute of k.

__global__ __launch_bounds__(256, 4) void gemm_mfma_kernel(
    const unsigned short* __restrict__ A, const unsigned short* __restrict__ B,
    const float* __restrict__ bias, float* __restrict__ out, int K) {
    __shared__ unsigned short S[2 * 8192];  // 2 buf x {A,B} x 128x32 bf16 = 32 KB
    const int bm = blockIdx.y * 128;
    const int bn = blockIdx.x * 128;
    const int tid = threadIdx.x;
    const int l = tid & 63;
    const int w = tid >> 6;
    const int wr = (w >> 1) * 64;
    const int wc = (w & 1) * 64;
    const int arow = l >> 2;        // staging row within 16-row chunk
    const int acol = (l & 3) * 8;   // staging bf16 col within BK=32

    const unsigned short* gA = A + (size_t)(bm + arow) * K + acol;
    const unsigned short* gB = B + (size_t)(bn + arow) * K + acol;

    f32x4 acc[4][4];
#pragma unroll
    for (int m = 0; m < 4; ++m)
#pragma unroll
        for (int n = 0; n < 4; ++n) acc[m][n] = (f32x4){0.f, 0.f, 0.f, 0.f};

    const int aoff = (wr + (l & 15)) * 32 + (l >> 4) * 8;
    const int woff = (wc + (l & 15)) * 32 + (l >> 4) * 8;
    const int ktiles = K >> 5;

    auto STAGE = [&](int buf, int kt) {
        unsigned short* lb = &S[buf * 8192];
#pragma unroll
        for (int i = 0; i < 2; ++i) {
            const int c = w * 2 + i;  // 16-row chunk, 0..7
            __builtin_amdgcn_global_load_lds(
                (const __attribute__((address_space(1))) void*)(gA + (size_t)(c * 16) * K + kt * 32),
                (__attribute__((address_space(3))) void*)(lb + c * 512), 16, 0, 0);
            __builtin_amdgcn_global_load_lds(
                (const __attribute__((address_space(1))) void*)(gB + (size_t)(c * 16) * K + kt * 32),
                (__attribute__((address_space(3))) void*)(lb + 4096 + c * 512), 16, 0, 0);
        }
    };

    STAGE(0, 0);
    __syncthreads();

    for (int kt = 0; kt < ktiles; ++kt) {
        if (kt + 1 < ktiles) STAGE((kt + 1) & 1, kt + 1);  // prefetch next tile
        const int sb = (kt & 1) * 8192;

        bf16x8 af[4], wf[4];
#pragma unroll
        for (int m = 0; m < 4; ++m)
            af[m] = *(const bf16x8*)&S[sb + aoff + m * 512];
#pragma unroll
        for (int n = 0; n < 4; ++n)
            wf[n] = *(const bf16x8*)&S[sb + 4096 + woff + n * 512];
#pragma unroll
        for (int m = 0; m < 4; ++m)
#pragma unroll
            for (int n = 0; n < 4; ++n)
                acc[m][n] = __builtin_amdgcn_mfma_f32_16x16x32_bf16(af[m], wf[n], acc[m][n], 0, 0, 0);
        __syncthreads();  // drains staged buf's vmcnt + protects buf just read
    }

    const int r0 = bm + wr + (l >> 4) * 4;
    const int c0 = bn + wc + (l & 15);
#pragma unroll
    for (int n = 0; n < 4; ++n) {
        const float bv = bias[c0 + n * 16];
#pragma unroll
        for (int m = 0; m < 4; ++m) {
#pragma unroll
            for (int j = 0; j < 4; ++j) {
                int gr = r0 + m * 16 + j;
                if (gr < N_NODES)
                    out[(size_t)gr * HID + c0 + n * 16] = acc[m][n][j] + bv;
            }
        }
    }
}

// ---------------- row L2-normalize + ELU (wave-per-row) ----------------
// FINAL=0: write bf16 feat into Fh (row stride 1024, feat-half of Cat2).
// FINAL=1: write f32 into outF (row stride 512).

template <int FINAL>
__global__ __launch_bounds__(256) void norm_elu_kernel(const float* __restrict__ in,
                                                       float* __restrict__ outF,
                                                       unsigned short* __restrict__ Fh) {
    const int wid = threadIdx.x >> 6;
    const int lane = threadIdx.x & 63;
    const int row = blockIdx.x * 4 + wid;
    if (row >= N_NODES) return;
    const float* p = in + (size_t)row * HID + lane * 8;
    float4 v0 = *(const float4*)p;
    float4 v1 = *(const float4*)(p + 4);
    float ss = v0.x * v0.x + v0.y * v0.y + v0.z * v0.z + v0.w * v0.w
             + v1.x * v1.x + v1.y * v1.y + v1.z * v1.z + v1.w * v1.w;
#pragma unroll
    for (int o = 32; o > 0; o >>= 1) ss += __shfl_xor(ss, o);
    float inv = 1.f / fmaxf(sqrtf(ss), 1e-12f);
    float r[8] = {v0.x, v0.y, v0.z, v0.w, v1.x, v1.y, v1.z, v1.w};
#pragma unroll
    for (int j = 0; j < 8; ++j) {
        r[j] *= inv;
        r[j] = r[j] > 0.f ? r[j] : expm1f(r[j]);
    }
    if (FINAL) {
        float* q = outF + (size_t)row * HID + lane * 8;
        *(float4*)q = make_float4(r[0], r[1], r[2], r[3]);
        *(float4*)(q + 4) = make_float4(r[4], r[5], r[6], r[7]);
    } else {
        unsigned short* q = Fh + (size_t)row * 1024 + lane * 8;
        u16x4 h0, h1;
#pragma unroll
        for (int j = 0; j < 4; ++j) { h0[j] = f2b(r[j]); h1[j] = f2b(r[4 + j]); }
        *(u16x4*)q = h0;
        *(u16x4*)(q + 4) = h1;
    }
}

// ---------------- launch ----------------

extern "C" void kernel_launch(void* const* d_in, const int* in_sizes, int n_in,
                              void* d_out, int out_size, void* d_ws, size_t ws_size,
                              hipStream_t stream) {
    const float* x    = (const float*)d_in[0];
    const void*  eidx = d_in[1];
    const float* Wl0 = (const float*)d_in[2];
    const float* bl0 = (const float*)d_in[3];
    const float* Wr0 = (const float*)d_in[4];
    const float* Wl1 = (const float*)d_in[5];
    const float* bl1 = (const float*)d_in[6];
    const float* Wr1 = (const float*)d_in[7];
    const float* Wl2 = (const float*)d_in[8];
    const float* bl2 = (const float*)d_in[9];
    const float* Wr2 = (const float*)d_in[10];
    float* outF = (float*)d_out;

    char* ws = (char*)d_ws;
    size_t o = 0;
    auto alloc = [&](size_t bytes) { void* p = ws + o; o += (bytes + 255) & ~(size_t)255; return p; };

    // Concat activation planes: Cat1 [M][512] (agg256|feat256),
    // Cat2 [M][1024] (agg512|feat512)
    unsigned short* Cat1 = (unsigned short*)alloc((size_t)M_PAD * 512 * 2);   // 51.25 MB
    unsigned short* Cat2 = (unsigned short*)alloc((size_t)M_PAD * 1024 * 2);  // 102.5 MB

    unsigned short* Wcat0 = (unsigned short*)alloc(512 * 512 * 2);
    unsigned short* Wcat1 = (unsigned short*)alloc(512 * 1024 * 2);
    unsigned short* Wcat2 = (unsigned short*)alloc(512 * 1024 * 2);

    // counts and cursor MUST be one contiguous block: zero_kernel clears
    // 2*N_NODES ints in one shot (R2/R3 crash: 256B alloc rounding left the
    // tail of a separately-alloc'd cursor poisoned -> giant atomicAdd pos ->
    // OOB edge_src writes -> GPU fault).
    int* counts   = (int*)alloc((size_t)2 * N_NODES * 4);
    int* cursor   = counts + N_NODES;
    int* offsets  = (int*)alloc((size_t)(N_NODES + 1) * 4);
    int* edge_src = (int*)alloc((size_t)N_EDGES * 4);
    int* flag     = (int*)alloc(256);

    // ---- CSR build ----
    zero_kernel<<<(2 * N_NODES + 255) / 256, 256, 0, stream>>>(counts, 2 * N_NODES);
    detect_kernel<<<1, 64, 0, stream>>>((const int*)eidx, flag);
    hist_kernel<<<(N_EDGES + 255) / 256, 256, 0, stream>>>(eidx, flag, counts);
    scan_kernel<<<1, 1024, 0, stream>>>(counts, offsets);
    fill_kernel<<<(N_EDGES + 255) / 256, 256, 0, stream>>>(eidx, flag, offsets, cursor, edge_src);

    // ---- conversions ----
    xconv_kernel<<<(M_PAD * 64 + 255) / 256, 256, 0, stream>>>(x, Cat1);
    wconv_kernel<<<512, 128, 0, stream>>>(Wl0, Wcat0, 256, 512, 0);
    wconv_kernel<<<512, 128, 0, stream>>>(Wr0, Wcat0, 256, 512, 256);
    wconv_kernel<<<512, 128, 0, stream>>>(Wl1, Wcat1, 512, 1024, 0);
    wconv_kernel<<<512, 128, 0, stream>>>(Wr1, Wcat1, 512, 1024, 512);
    wconv_kernel<<<512, 128, 0, stream>>>(Wl2, Wcat2, 512, 1024, 0);
    wconv_kernel<<<512, 128, 0, stream>>>(Wr2, Wcat2, 512, 1024, 512);

    dim3 ggrid(4, M_PAD / 128);           // (512/128, 391)
    const int ngrid = (N_NODES + 3) / 4;  // 4 rows per 256-block

    // layer 1 (feat 256): Cat1 = agg|x, K=512
    aggregate_kernel<4><<<ngrid, 256, 0, stream>>>(Cat1 + 256, offsets, edge_src, Cat1);
    gemm_mfma_kernel<<<ggrid, 256, 0, stream>>>(Cat1, Wcat0, bl0, outF, 512);
    norm_elu_kernel<0><<<ngrid, 256, 0, stream>>>(outF, nullptr, Cat2 + 512);

    // layer 2 (feat 512): Cat2 = agg|feat, K=1024
    aggregate_kernel<8><<<ngrid, 256, 0, stream>>>(Cat2 + 512, offsets, edge_src, Cat2);
    gemm_mfma_kernel<<<ggrid, 256, 0, stream>>>(Cat2, Wcat1, bl1, outF, 1024);
    norm_elu_kernel<0><<<ngrid, 256, 0, stream>>>(outF, nullptr, Cat2 + 512);

    // layer 3 (feat 512)
    aggregate_kernel<8><<<ngrid, 256, 0, stream>>>(Cat2 + 512, offsets, edge_src, Cat2);
    gemm_mfma_kernel<<<ggrid, 256, 0, stream>>>(Cat2, Wcat2, bl2, outF, 1024);
    norm_elu_kernel<1><<<ngrid, 256, 0, stream>>>(outF, outF, nullptr);

    (void)in_sizes; (void)n_in; (void)out_size; (void)ws_size;
}